// Round 1
// baseline (1322.544 us; speedup 1.0000x reference)
//
#include <hip/hip_runtime.h>

#define N_NODES 100000
#define N_EDGES 1280000
#define HID 64
#define N_ETYPE 8

// ---- workspace byte offsets (all 128B-aligned) ----
#define WS_HT    0ull            // 8*N*64 f32 = 204,800,000 B
#define WS_MAGG  204800000ull    // N*64 f32   =  25,600,000 B
#define WS_OFFS  230400000ull    // N i32
#define WS_DEG   230800000ull    // N i32
#define WS_CUR   231200000ull    // N i32
#define WS_CSR   231600000ull    // E i32 = 5,120,000 B
#define WS_BSUM  236720000ull    // 128 i32
#define WS_BOFF  236720512ull    // 128 i32
// total ~236.8 MB

// ---------------------------------------------------------------------------
// K1: Ht[t][n][m] = sum_h A[t][m][h] * h[n][h]
// wave-per-16-nodes; lane = m; A row in 64 VGPRs; h rows via scalar loads.
// ---------------------------------------------------------------------------
__global__ void k1_ht(const float* __restrict__ h, const float* __restrict__ em,
                      float* __restrict__ Ht) {
    int gwave = (int)((blockIdx.x * blockDim.x + threadIdx.x) >> 6);
    int lane  = threadIdx.x & 63;
    int n0 = __builtin_amdgcn_readfirstlane(gwave << 4);
    if (n0 >= N_NODES) return;
    #pragma unroll 1
    for (int t = 0; t < N_ETYPE; ++t) {
        float a[64];
        const float4* ar = (const float4*)(em + (size_t)t * 4096 + (size_t)lane * 64);
        #pragma unroll
        for (int q = 0; q < 16; ++q) {
            float4 v = ar[q];
            a[4*q+0] = v.x; a[4*q+1] = v.y; a[4*q+2] = v.z; a[4*q+3] = v.w;
        }
        #pragma unroll 1
        for (int n = n0; n < n0 + 16; ++n) {
            const float4* hr = (const float4*)(h + (size_t)n * HID);
            float s0 = 0.f, s1 = 0.f, s2 = 0.f, s3 = 0.f;
            #pragma unroll
            for (int q = 0; q < 16; ++q) {
                float4 v = hr[q];
                s0 = fmaf(a[4*q+0], v.x, s0);
                s1 = fmaf(a[4*q+1], v.y, s1);
                s2 = fmaf(a[4*q+2], v.z, s2);
                s3 = fmaf(a[4*q+3], v.w, s3);
            }
            Ht[((size_t)t * N_NODES + n) * HID + lane] = (s0 + s1) + (s2 + s3);
        }
    }
}

// ---------------------------------------------------------------------------
// CSR build: histogram -> 2-level exclusive scan -> fill
// ---------------------------------------------------------------------------
__global__ void k_hist(const int* __restrict__ dst, int* __restrict__ deg) {
    int e = blockIdx.x * blockDim.x + threadIdx.x;
    if (e < N_EDGES) atomicAdd(&deg[dst[e]], 1);
}

__global__ void k_scan_a(const int* __restrict__ deg, int* __restrict__ offs,
                         int* __restrict__ bsum) {
    __shared__ int sh[256];
    int tid  = threadIdx.x;
    int base = blockIdx.x * 1024 + tid * 4;
    int d0 = (base + 0 < N_NODES) ? deg[base + 0] : 0;
    int d1 = (base + 1 < N_NODES) ? deg[base + 1] : 0;
    int d2 = (base + 2 < N_NODES) ? deg[base + 2] : 0;
    int d3 = (base + 3 < N_NODES) ? deg[base + 3] : 0;
    int s = d0 + d1 + d2 + d3;
    sh[tid] = s;
    __syncthreads();
    for (int ofs = 1; ofs < 256; ofs <<= 1) {
        int v = (tid >= ofs) ? sh[tid - ofs] : 0;
        __syncthreads();
        sh[tid] += v;
        __syncthreads();
    }
    int excl = sh[tid] - s;
    if (base + 0 < N_NODES) offs[base + 0] = excl;
    if (base + 1 < N_NODES) offs[base + 1] = excl + d0;
    if (base + 2 < N_NODES) offs[base + 2] = excl + d0 + d1;
    if (base + 3 < N_NODES) offs[base + 3] = excl + d0 + d1 + d2;
    if (tid == 255) bsum[blockIdx.x] = sh[255];
}

__global__ void k_scan_b(const int* __restrict__ bsum, int* __restrict__ boff) {
    __shared__ int sh[128];
    int tid = threadIdx.x;                 // 128 threads, NB = 98
    int v = (tid < 98) ? bsum[tid] : 0;
    sh[tid] = v;
    __syncthreads();
    for (int ofs = 1; ofs < 128; ofs <<= 1) {
        int u = (tid >= ofs) ? sh[tid - ofs] : 0;
        __syncthreads();
        sh[tid] += u;
        __syncthreads();
    }
    if (tid < 98) boff[tid] = sh[tid] - v;
}

__global__ void k_scan_c(int* __restrict__ offs, const int* __restrict__ boff,
                         int* __restrict__ cur) {
    int tid  = threadIdx.x;
    int add  = boff[blockIdx.x];
    int base = blockIdx.x * 1024 + tid * 4;
    #pragma unroll
    for (int q = 0; q < 4; ++q) {
        int i = base + q;
        if (i < N_NODES) { int v = offs[i] + add; offs[i] = v; cur[i] = v; }
    }
}

__global__ void k_fill(const int* __restrict__ src, const int* __restrict__ dst,
                       const int* __restrict__ typ, int* __restrict__ cur,
                       int* __restrict__ csr) {
    int e = blockIdx.x * blockDim.x + threadIdx.x;
    if (e < N_EDGES) {
        int d = dst[e];
        int p = atomicAdd(&cur[d], 1);
        csr[p] = typ[e] * N_NODES + src[e];
    }
}

// ---------------------------------------------------------------------------
// K4: m_agg[d][m] = sum over in-edges of Ht[type][src][m]; wave per node.
// ---------------------------------------------------------------------------
__global__ void k_agg(const float* __restrict__ Ht, const int* __restrict__ offs,
                      const int* __restrict__ deg, const int* __restrict__ csr,
                      float* __restrict__ magg) {
    int gwave = (int)((blockIdx.x * blockDim.x + threadIdx.x) >> 6);
    int lane  = threadIdx.x & 63;
    int d = __builtin_amdgcn_readfirstlane(gwave);
    if (d >= N_NODES) return;
    int off = offs[d];
    int cnt = deg[d];
    float acc0 = 0.f, acc1 = 0.f;
    int k = 0;
    for (; k + 1 < cnt; k += 2) {
        int i0 = csr[off + k];
        int i1 = csr[off + k + 1];
        acc0 += Ht[(size_t)i0 * HID + lane];
        acc1 += Ht[(size_t)i1 * HID + lane];
    }
    if (k < cnt) acc0 += Ht[(size_t)csr[off + k] * HID + lane];
    magg[(size_t)d * HID + lane] = acc0 + acc1;
}

// ---------------------------------------------------------------------------
// K5: fused GRU. 6 waves/block; wave g owns weight rows g*64..g*64+63 of
// [w_ih; w_hh] in VGPRs; gate values exchanged through LDS; combine+store.
// ---------------------------------------------------------------------------
__global__ __launch_bounds__(384) void k_gru(
        const float* __restrict__ h, const float* __restrict__ magg,
        const float* __restrict__ w_ih, const float* __restrict__ w_hh,
        const float* __restrict__ b_ih, const float* __restrict__ b_hh,
        float* __restrict__ out) {
    __shared__ float g_lds[6][16][HID];
    int tid  = threadIdx.x;
    int lane = tid & 63;
    int g = __builtin_amdgcn_readfirstlane(tid >> 6);   // 0..5

    const float* wrow = (g < 3) ? (w_ih + (size_t)(g * 64 + lane) * 64)
                                : (w_hh + (size_t)((g - 3) * 64 + lane) * 64);
    float w[64];
    const float4* wr4 = (const float4*)wrow;
    #pragma unroll
    for (int q = 0; q < 16; ++q) {
        float4 v = wr4[q];
        w[4*q+0] = v.x; w[4*q+1] = v.y; w[4*q+2] = v.z; w[4*q+3] = v.w;
    }
    float bias = (g < 3) ? b_ih[g * 64 + lane] : b_hh[(g - 3) * 64 + lane];
    const float* vin = (g < 3) ? magg : h;

    const int n_tiles = N_NODES / 16;   // 6250
    for (int tile = blockIdx.x; tile < n_tiles; tile += gridDim.x) {
        int nb = tile * 16;
        #pragma unroll 1
        for (int n = 0; n < 16; ++n) {
            const float4* vr = (const float4*)(vin + (size_t)(nb + n) * HID);
            float s0 = bias, s1 = 0.f, s2 = 0.f, s3 = 0.f;
            #pragma unroll
            for (int q = 0; q < 16; ++q) {
                float4 v = vr[q];
                s0 = fmaf(w[4*q+0], v.x, s0);
                s1 = fmaf(w[4*q+1], v.y, s1);
                s2 = fmaf(w[4*q+2], v.z, s2);
                s3 = fmaf(w[4*q+3], v.w, s3);
            }
            g_lds[g][n][lane] = (s0 + s1) + (s2 + s3);
        }
        __syncthreads();
        for (int idx = tid; idx < 16 * HID; idx += 384) {
            int n = idx >> 6, j = idx & 63;
            float gir = g_lds[0][n][j], giz = g_lds[1][n][j], gin = g_lds[2][n][j];
            float ghr = g_lds[3][n][j], ghz = g_lds[4][n][j], ghn = g_lds[5][n][j];
            float hv  = h[(size_t)(nb + n) * HID + j];
            float r  = 1.f / (1.f + __expf(-(gir + ghr)));
            float z  = 1.f / (1.f + __expf(-(giz + ghz)));
            float nn = tanhf(gin + r * ghn);
            out[(size_t)(nb + n) * HID + j] = (1.f - z) * nn + z * hv;
        }
        __syncthreads();
    }
}

// ---------------------------------------------------------------------------
extern "C" void kernel_launch(void* const* d_in, const int* in_sizes, int n_in,
                              void* d_out, int out_size, void* d_ws, size_t ws_size,
                              hipStream_t stream) {
    const float* h    = (const float*)d_in[0];
    const float* em   = (const float*)d_in[1];
    const float* w_ih = (const float*)d_in[2];
    const float* w_hh = (const float*)d_in[3];
    const float* b_ih = (const float*)d_in[4];
    const float* b_hh = (const float*)d_in[5];
    const int* e_src  = (const int*)d_in[6];
    const int* e_dst  = (const int*)d_in[7];
    const int* e_typ  = (const int*)d_in[8];
    float* out = (float*)d_out;

    char* ws = (char*)d_ws;
    float* Ht   = (float*)(ws + WS_HT);
    float* magg = (float*)(ws + WS_MAGG);
    int* offs = (int*)(ws + WS_OFFS);
    int* deg  = (int*)(ws + WS_DEG);
    int* cur  = (int*)(ws + WS_CUR);
    int* csr  = (int*)(ws + WS_CSR);
    int* bsum = (int*)(ws + WS_BSUM);
    int* boff = (int*)(ws + WS_BOFF);

    hipMemsetAsync(deg, 0, (size_t)N_NODES * sizeof(int), stream);

    // Ht GEMM: 6250 waves, 4 waves/block
    k1_ht<<<1563, 256, 0, stream>>>(h, em, Ht);

    // CSR build
    k_hist<<<N_EDGES / 256, 256, 0, stream>>>(e_dst, deg);
    k_scan_a<<<98, 256, 0, stream>>>(deg, offs, bsum);
    k_scan_b<<<1, 128, 0, stream>>>(bsum, boff);
    k_scan_c<<<98, 256, 0, stream>>>(offs, boff, cur);
    k_fill<<<N_EDGES / 256, 256, 0, stream>>>(e_src, e_dst, e_typ, cur, csr);

    // aggregate: 100000 waves, 4 waves/block
    k_agg<<<25000, 256, 0, stream>>>(Ht, offs, deg, csr, magg);

    // fused GRU
    k_gru<<<1024, 384, 0, stream>>>(h, magg, w_ih, w_hh, b_ih, b_hh, out);
}

// Round 2
// 1043.785 us; speedup vs baseline: 1.2671x; 1.2671x over previous
//
#include <hip/hip_runtime.h>

#define N_NODES 100000
#define N_EDGES 1280000
#define HID 64
#define N_ETYPE 8

// ---- workspace byte offsets (all 128B-aligned) ----
#define WS_HT    0ull            // 8*N*64 f32 = 204,800,000 B
#define WS_MAGG  204800000ull    // N*64 f32   =  25,600,000 B
#define WS_OFFS  230400000ull    // N i32
#define WS_DEG   230800000ull    // N i32
#define WS_CUR   231200000ull    // N i32
#define WS_CSR   231600000ull    // E i32 = 5,120,000 B
#define WS_BSUM  236720000ull    // 128 i32
#define WS_BOFF  236720512ull    // 128 i32
// total ~236.8 MB

// ---------------------------------------------------------------------------
// K1 v2: Ht[t][n][m] = sum_h A[t][m][h] * h[n][h]
// wave = (t, block of 128 nodes). A row (lane=m) lives in 64 VGPRs, loaded
// ONCE per wave. h-row loads are wave-uniform (scalar-friendly). Fixes the
// 800MB em re-fetch of v1 (FETCH was 775MB, ideal ~230MB total).
// ---------------------------------------------------------------------------
#define K1_NODES_PER_WAVE 128
#define K1_NB 782                      // ceil(100000/128)

__global__ __launch_bounds__(256) void k1_ht(const float* __restrict__ h,
                                             const float* __restrict__ em,
                                             float* __restrict__ Ht) {
    int gw = __builtin_amdgcn_readfirstlane((blockIdx.x * 256 + (int)threadIdx.x) >> 6);
    int lane = threadIdx.x & 63;
    int t  = gw / K1_NB;               // 0..7
    int nb = gw - t * K1_NB;           // 0..781
    if (t >= N_ETYPE) return;
    int n0 = nb * K1_NODES_PER_WAVE;
    int n1 = n0 + K1_NODES_PER_WAVE;
    if (n1 > N_NODES) n1 = N_NODES;

    // A[t][lane][0..63] -> 64 VGPRs (one-time, 16KB per wave, L2-hot)
    float a[64];
    const float4* ar = (const float4*)(em + (size_t)t * 4096 + (size_t)lane * 64);
    #pragma unroll
    for (int q = 0; q < 16; ++q) {
        float4 v = ar[q];
        a[4*q+0] = v.x; a[4*q+1] = v.y; a[4*q+2] = v.z; a[4*q+3] = v.w;
    }

    float* outp = Ht + (size_t)t * N_NODES * HID;
    #pragma unroll 2
    for (int n = n0; n < n1; ++n) {
        const float4* hr = (const float4*)(h + (size_t)n * HID);
        float s0 = 0.f, s1 = 0.f, s2 = 0.f, s3 = 0.f;
        #pragma unroll
        for (int q = 0; q < 16; ++q) {
            float4 v = hr[q];
            s0 = fmaf(a[4*q+0], v.x, s0);
            s1 = fmaf(a[4*q+1], v.y, s1);
            s2 = fmaf(a[4*q+2], v.z, s2);
            s3 = fmaf(a[4*q+3], v.w, s3);
        }
        outp[(size_t)n * HID + lane] = (s0 + s1) + (s2 + s3);
    }
}

// ---------------------------------------------------------------------------
// CSR build: histogram -> 2-level exclusive scan -> fill
// ---------------------------------------------------------------------------
__global__ void k_hist(const int* __restrict__ dst, int* __restrict__ deg) {
    int e = blockIdx.x * blockDim.x + threadIdx.x;
    if (e < N_EDGES) atomicAdd(&deg[dst[e]], 1);
}

__global__ void k_scan_a(const int* __restrict__ deg, int* __restrict__ offs,
                         int* __restrict__ bsum) {
    __shared__ int sh[256];
    int tid  = threadIdx.x;
    int base = blockIdx.x * 1024 + tid * 4;
    int d0 = (base + 0 < N_NODES) ? deg[base + 0] : 0;
    int d1 = (base + 1 < N_NODES) ? deg[base + 1] : 0;
    int d2 = (base + 2 < N_NODES) ? deg[base + 2] : 0;
    int d3 = (base + 3 < N_NODES) ? deg[base + 3] : 0;
    int s = d0 + d1 + d2 + d3;
    sh[tid] = s;
    __syncthreads();
    for (int ofs = 1; ofs < 256; ofs <<= 1) {
        int v = (tid >= ofs) ? sh[tid - ofs] : 0;
        __syncthreads();
        sh[tid] += v;
        __syncthreads();
    }
    int excl = sh[tid] - s;
    if (base + 0 < N_NODES) offs[base + 0] = excl;
    if (base + 1 < N_NODES) offs[base + 1] = excl + d0;
    if (base + 2 < N_NODES) offs[base + 2] = excl + d0 + d1;
    if (base + 3 < N_NODES) offs[base + 3] = excl + d0 + d1 + d2;
    if (tid == 255) bsum[blockIdx.x] = sh[255];
}

__global__ void k_scan_b(const int* __restrict__ bsum, int* __restrict__ boff) {
    __shared__ int sh[128];
    int tid = threadIdx.x;                 // 128 threads, NB = 98
    int v = (tid < 98) ? bsum[tid] : 0;
    sh[tid] = v;
    __syncthreads();
    for (int ofs = 1; ofs < 128; ofs <<= 1) {
        int u = (tid >= ofs) ? sh[tid - ofs] : 0;
        __syncthreads();
        sh[tid] += u;
        __syncthreads();
    }
    if (tid < 98) boff[tid] = sh[tid] - v;
}

__global__ void k_scan_c(int* __restrict__ offs, const int* __restrict__ boff,
                         int* __restrict__ cur) {
    int tid  = threadIdx.x;
    int add  = boff[blockIdx.x];
    int base = blockIdx.x * 1024 + tid * 4;
    #pragma unroll
    for (int q = 0; q < 4; ++q) {
        int i = base + q;
        if (i < N_NODES) { int v = offs[i] + add; offs[i] = v; cur[i] = v; }
    }
}

__global__ void k_fill(const int* __restrict__ src, const int* __restrict__ dst,
                       const int* __restrict__ typ, int* __restrict__ cur,
                       int* __restrict__ csr) {
    int e = blockIdx.x * blockDim.x + threadIdx.x;
    if (e < N_EDGES) {
        int d = dst[e];
        int p = atomicAdd(&cur[d], 1);
        csr[p] = typ[e] * N_NODES + src[e];
    }
}

// ---------------------------------------------------------------------------
// K4: m_agg[d][m] = sum over in-edges of Ht[type][src][m]; wave per node.
// ---------------------------------------------------------------------------
__global__ void k_agg(const float* __restrict__ Ht, const int* __restrict__ offs,
                      const int* __restrict__ deg, const int* __restrict__ csr,
                      float* __restrict__ magg) {
    int gwave = (int)((blockIdx.x * blockDim.x + threadIdx.x) >> 6);
    int lane  = threadIdx.x & 63;
    int d = __builtin_amdgcn_readfirstlane(gwave);
    if (d >= N_NODES) return;
    int off = offs[d];
    int cnt = deg[d];
    float acc0 = 0.f, acc1 = 0.f;
    int k = 0;
    for (; k + 1 < cnt; k += 2) {
        int i0 = csr[off + k];
        int i1 = csr[off + k + 1];
        acc0 += Ht[(size_t)i0 * HID + lane];
        acc1 += Ht[(size_t)i1 * HID + lane];
    }
    if (k < cnt) acc0 += Ht[(size_t)csr[off + k] * HID + lane];
    magg[(size_t)d * HID + lane] = acc0 + acc1;
}

// ---------------------------------------------------------------------------
// K5: fused GRU. 6 waves/block; wave g owns weight rows g*64..g*64+63 of
// [w_ih; w_hh] in VGPRs; gate values exchanged through LDS; combine+store.
// ---------------------------------------------------------------------------
__global__ __launch_bounds__(384) void k_gru(
        const float* __restrict__ h, const float* __restrict__ magg,
        const float* __restrict__ w_ih, const float* __restrict__ w_hh,
        const float* __restrict__ b_ih, const float* __restrict__ b_hh,
        float* __restrict__ out) {
    __shared__ float g_lds[6][16][HID];
    int tid  = threadIdx.x;
    int lane = tid & 63;
    int g = __builtin_amdgcn_readfirstlane(tid >> 6);   // 0..5

    const float* wrow = (g < 3) ? (w_ih + (size_t)(g * 64 + lane) * 64)
                                : (w_hh + (size_t)((g - 3) * 64 + lane) * 64);
    float w[64];
    const float4* wr4 = (const float4*)wrow;
    #pragma unroll
    for (int q = 0; q < 16; ++q) {
        float4 v = wr4[q];
        w[4*q+0] = v.x; w[4*q+1] = v.y; w[4*q+2] = v.z; w[4*q+3] = v.w;
    }
    float bias = (g < 3) ? b_ih[g * 64 + lane] : b_hh[(g - 3) * 64 + lane];
    const float* vin = (g < 3) ? magg : h;

    const int n_tiles = N_NODES / 16;   // 6250
    for (int tile = blockIdx.x; tile < n_tiles; tile += gridDim.x) {
        int nb = tile * 16;
        #pragma unroll 1
        for (int n = 0; n < 16; ++n) {
            const float4* vr = (const float4*)(vin + (size_t)(nb + n) * HID);
            float s0 = bias, s1 = 0.f, s2 = 0.f, s3 = 0.f;
            #pragma unroll
            for (int q = 0; q < 16; ++q) {
                float4 v = vr[q];
                s0 = fmaf(w[4*q+0], v.x, s0);
                s1 = fmaf(w[4*q+1], v.y, s1);
                s2 = fmaf(w[4*q+2], v.z, s2);
                s3 = fmaf(w[4*q+3], v.w, s3);
            }
            g_lds[g][n][lane] = (s0 + s1) + (s2 + s3);
        }
        __syncthreads();
        for (int idx = tid; idx < 16 * HID; idx += 384) {
            int n = idx >> 6, j = idx & 63;
            float gir = g_lds[0][n][j], giz = g_lds[1][n][j], gin = g_lds[2][n][j];
            float ghr = g_lds[3][n][j], ghz = g_lds[4][n][j], ghn = g_lds[5][n][j];
            float hv  = h[(size_t)(nb + n) * HID + j];
            float r  = 1.f / (1.f + __expf(-(gir + ghr)));
            float z  = 1.f / (1.f + __expf(-(giz + ghz)));
            float nn = tanhf(gin + r * ghn);
            out[(size_t)(nb + n) * HID + j] = (1.f - z) * nn + z * hv;
        }
        __syncthreads();
    }
}

// ---------------------------------------------------------------------------
extern "C" void kernel_launch(void* const* d_in, const int* in_sizes, int n_in,
                              void* d_out, int out_size, void* d_ws, size_t ws_size,
                              hipStream_t stream) {
    const float* h    = (const float*)d_in[0];
    const float* em   = (const float*)d_in[1];
    const float* w_ih = (const float*)d_in[2];
    const float* w_hh = (const float*)d_in[3];
    const float* b_ih = (const float*)d_in[4];
    const float* b_hh = (const float*)d_in[5];
    const int* e_src  = (const int*)d_in[6];
    const int* e_dst  = (const int*)d_in[7];
    const int* e_typ  = (const int*)d_in[8];
    float* out = (float*)d_out;

    char* ws = (char*)d_ws;
    float* Ht   = (float*)(ws + WS_HT);
    float* magg = (float*)(ws + WS_MAGG);
    int* offs = (int*)(ws + WS_OFFS);
    int* deg  = (int*)(ws + WS_DEG);
    int* cur  = (int*)(ws + WS_CUR);
    int* csr  = (int*)(ws + WS_CSR);
    int* bsum = (int*)(ws + WS_BSUM);
    int* boff = (int*)(ws + WS_BOFF);

    hipMemsetAsync(deg, 0, (size_t)N_NODES * sizeof(int), stream);

    // Ht GEMM: 8t x 782 node-blocks = 6256 waves, 4 waves/block
    k1_ht<<<1564, 256, 0, stream>>>(h, em, Ht);

    // CSR build
    k_hist<<<N_EDGES / 256, 256, 0, stream>>>(e_dst, deg);
    k_scan_a<<<98, 256, 0, stream>>>(deg, offs, bsum);
    k_scan_b<<<1, 128, 0, stream>>>(bsum, boff);
    k_scan_c<<<98, 256, 0, stream>>>(offs, boff, cur);
    k_fill<<<N_EDGES / 256, 256, 0, stream>>>(e_src, e_dst, e_typ, cur, csr);

    // aggregate: 100000 waves, 4 waves/block
    k_agg<<<25000, 256, 0, stream>>>(Ht, offs, deg, csr, magg);

    // fused GRU
    k_gru<<<1024, 384, 0, stream>>>(h, magg, w_ih, w_hh, b_ih, b_hh, out);
}